// Round 1
// baseline (731.053 us; speedup 1.0000x reference)
//
#include <hip/hip_runtime.h>
#include <hip/hip_bf16.h>

#define NEG_ATT 0.2f
#define NEG_ACT 0.01f

// ---------------- CSR build ----------------

__global__ void init_deg(int* deg, int Nn) {
    int t = blockIdx.x * 256 + threadIdx.x;
    if (t < Nn) deg[t] = 1;  // self loop
}

__global__ void count_edges(const int* __restrict__ ei, int* deg, int E) {
    int t = blockIdx.x * 256 + threadIdx.x;
    if (t < E) atomicAdd(&deg[ei[E + t]], 1);  // dst row
}

#define SCAN_CHUNK 1024
__global__ void scan1(const int* __restrict__ deg, int* __restrict__ offs,
                      int* blocksum, int Nn) {
    __shared__ int sh[256];
    int b = blockIdx.x, t = threadIdx.x;
    int base = b * SCAN_CHUNK + t * 4;
    int v[4];
    int s = 0;
    for (int j = 0; j < 4; j++) {
        int idx = base + j;
        v[j] = (idx < Nn) ? deg[idx] : 0;
        s += v[j];
    }
    sh[t] = s;
    __syncthreads();
    for (int off = 1; off < 256; off <<= 1) {
        int x = (t >= off) ? sh[t - off] : 0;
        __syncthreads();
        sh[t] += x;
        __syncthreads();
    }
    int excl = sh[t] - s;
    if (t == 255) blocksum[b] = sh[255];
    int run = excl;
    for (int j = 0; j < 4; j++) {
        int idx = base + j;
        if (idx < Nn) offs[idx] = run;
        run += v[j];
    }
}

__global__ void scan2(int* blocksum, int G) {
    if (threadIdx.x == 0 && blockIdx.x == 0) {
        int run = 0;
        for (int i = 0; i < G; i++) { int v = blocksum[i]; blocksum[i] = run; run += v; }
    }
}

__global__ void scan3(int* offs, const int* base, int* cursor, int Nn, int total) {
    int i = blockIdx.x * 256 + threadIdx.x;
    if (i < Nn) {
        int v = offs[i] + base[i >> 10];
        offs[i] = v;
        cursor[i] = v;
    }
    if (i == 0) offs[Nn] = total;
}

__global__ void fill_csr(const int* __restrict__ ei, int* cursor, int* csr, int E, int Nn) {
    int t = blockIdx.x * 256 + threadIdx.x;
    if (t < E) {
        int s = ei[t];
        int d = ei[E + t];
        int p = atomicAdd(&cursor[d], 1);
        csr[p] = s;
    } else if (t < E + Nn) {
        int nn = t - E;
        int p = atomicAdd(&cursor[nn], 1);
        csr[p] = nn;
    }
}

// ---------------- GEMM (TN): H[m,o] = sum_k X[m,k] * W[o,k] ----------------
// X: [M,K] row-major, W: [CO,K] row-major. BM=BN=64, BK=16, 256 thr, 4x4/thr.

template <int K, int CO>
__global__ __launch_bounds__(256) void gemm_tn(const float* __restrict__ X,
                                               const float* __restrict__ W,
                                               float* __restrict__ Hout, int M) {
    constexpr int BM = 64, BK = 16, LDA = BM + 4;  // pad 4 -> 2-way max conflicts
    __shared__ float As[BK][LDA];
    __shared__ float Bs[BK][LDA];
    int tid = threadIdx.x;
    int tx = tid & 15, ty = tid >> 4;
    int m0 = blockIdx.x * BM;
    int n0 = blockIdx.y * 64;
    int lr = tid >> 2;         // 0..63 row within tile
    int lk = (tid & 3) * 4;    // k offset (float4)
    float acc[4][4] = {};
    for (int k0 = 0; k0 < K; k0 += BK) {
        int m = m0 + lr;
        float4 av = (m < M) ? *(const float4*)&X[(size_t)m * K + k0 + lk]
                            : make_float4(0.f, 0.f, 0.f, 0.f);
        float4 bv = *(const float4*)&W[(size_t)(n0 + lr) * K + k0 + lk];
        __syncthreads();
        As[lk + 0][lr] = av.x; As[lk + 1][lr] = av.y;
        As[lk + 2][lr] = av.z; As[lk + 3][lr] = av.w;
        Bs[lk + 0][lr] = bv.x; Bs[lk + 1][lr] = bv.y;
        Bs[lk + 2][lr] = bv.z; Bs[lk + 3][lr] = bv.w;
        __syncthreads();
#pragma unroll
        for (int kk = 0; kk < BK; kk++) {
            float4 a = *(const float4*)&As[kk][ty * 4];
            float4 b = *(const float4*)&Bs[kk][tx * 4];
            float ar[4] = {a.x, a.y, a.z, a.w};
            float br[4] = {b.x, b.y, b.z, b.w};
#pragma unroll
            for (int i = 0; i < 4; i++)
#pragma unroll
                for (int j = 0; j < 4; j++) acc[i][j] += ar[i] * br[j];
        }
    }
#pragma unroll
    for (int i = 0; i < 4; i++) {
        int m = m0 + ty * 4 + i;
        if (m < M) {
            float4 o = make_float4(acc[i][0], acc[i][1], acc[i][2], acc[i][3]);
            *(float4*)&Hout[(size_t)m * CO + n0 + tx * 4] = o;
        }
    }
}

// ---------------- attention logits per node ----------------

template <int HEADS>
__global__ void compute_al(const float* __restrict__ Hmat, const float* __restrict__ a_s,
                           const float* __restrict__ a_d, float* als, float* ald, int Nn) {
    int n = blockIdx.x;
    int hd = threadIdx.x >> 6;
    int lane = threadIdx.x & 63;
    float v = Hmat[(size_t)n * (HEADS * 64) + hd * 64 + lane];
    float ps = v * a_s[hd * 64 + lane];
    float pd = v * a_d[hd * 64 + lane];
    for (int off = 32; off; off >>= 1) {
        ps += __shfl_down(ps, off);
        pd += __shfl_down(pd, off);
    }
    if (lane == 0) {
        als[n * HEADS + hd] = ps;
        ald[n * HEADS + hd] = pd;
    }
}

// ---------------- edge-softmax aggregation (one wave per node) ----------------

__global__ __launch_bounds__(256) void aggregate_h4(
    const float* __restrict__ Hmat, const float* __restrict__ als,
    const float* __restrict__ ald, const int* __restrict__ offs,
    const int* __restrict__ csr, const float* __restrict__ bias,
    float* __restrict__ Yout, int Nn) {
    int wave = threadIdx.x >> 6;
    int lane = threadIdx.x & 63;
    int n = blockIdx.x * 4 + wave;
    if (n >= Nn) return;
    int hd = lane >> 4;     // head for my 4 channels
    int c4 = lane * 4;      // channel base 0..252
    float aldn = ald[n * 4 + hd];
    int beg = offs[n], end = offs[n + 1];
    float4 acc = make_float4(0.f, 0.f, 0.f, 0.f);
    float den = 0.f;
    for (int i = beg; i < end; i++) {
        int s = csr[i];
        float e = als[s * 4 + hd] + aldn;
        e = e > 0.f ? e : NEG_ATT * e;
        float w = __expf(e);
        den += w;
        float4 hv = *(const float4*)&Hmat[(size_t)s * 256 + c4];
        acc.x += w * hv.x; acc.y += w * hv.y;
        acc.z += w * hv.z; acc.w += w * hv.w;
    }
    float inv = 1.f / den;
    float4 bv = *(const float4*)&bias[c4];
    float4 o = make_float4(acc.x * inv + bv.x, acc.y * inv + bv.y,
                           acc.z * inv + bv.z, acc.w * inv + bv.w);
    *(float4*)&Yout[(size_t)n * 256 + c4] = o;
}

__global__ __launch_bounds__(256) void aggregate_h1(
    const float* __restrict__ Hmat, const float* __restrict__ als,
    const float* __restrict__ ald, const int* __restrict__ offs,
    const int* __restrict__ csr, const float* __restrict__ bias,
    float* __restrict__ Yout, int Nn) {
    int wave = threadIdx.x >> 6;
    int lane = threadIdx.x & 63;
    int n = blockIdx.x * 4 + wave;
    if (n >= Nn) return;
    float aldn = ald[n];
    int beg = offs[n], end = offs[n + 1];
    float acc = 0.f, den = 0.f;
    for (int i = beg; i < end; i++) {
        int s = csr[i];
        float e = als[s] + aldn;
        e = e > 0.f ? e : NEG_ATT * e;
        float w = __expf(e);
        den += w;
        acc += w * Hmat[(size_t)s * 64 + lane];
    }
    Yout[(size_t)n * 64 + lane] = acc / den + bias[lane];
}

// ---------------- BatchNorm (training-mode, biased var) ----------------

__global__ void zero_bn(float* gsum, float* gsq) {
    gsum[threadIdx.x] = 0.f;
    gsq[threadIdx.x] = 0.f;
}

__global__ __launch_bounds__(256) void bn_stats(const float* __restrict__ Y,
                                                float* gsum, float* gsq, int Nn) {
    int ch = threadIdx.x;
    int rows_per = (Nn + gridDim.x - 1) / gridDim.x;
    int r0 = blockIdx.x * rows_per;
    int r1 = r0 + rows_per;
    if (r1 > Nn) r1 = Nn;
    float s = 0.f, q = 0.f;
    for (int r = r0; r < r1; r++) {
        float v = Y[(size_t)r * 256 + ch];
        s += v;
        q += v * v;
    }
    atomicAdd(&gsum[ch], s);
    atomicAdd(&gsq[ch], q);
}

__global__ void bn_final(const float* gsum, const float* gsq, const float* __restrict__ gamma,
                         const float* __restrict__ beta, float* scale, float* shift, int Nn) {
    int ch = threadIdx.x;
    float inv_n = 1.f / (float)Nn;
    float mu = gsum[ch] * inv_n;
    float var = gsq[ch] * inv_n - mu * mu;
    float sc = gamma[ch] * rsqrtf(var + 1e-5f);
    scale[ch] = sc;
    shift[ch] = beta[ch] - mu * sc;
}

template <bool RES>
__global__ __launch_bounds__(256) void bn_apply(const float* __restrict__ Y,
                                                const float* __restrict__ scale,
                                                const float* __restrict__ shift,
                                                const float* __restrict__ Res,
                                                float* __restrict__ Out, int total4) {
    int i = blockIdx.x * 256 + threadIdx.x;
    if (i >= total4) return;
    float4 v = ((const float4*)Y)[i];
    int cb = (i * 4) & 255;
    float4 sc = *(const float4*)&scale[cb];
    float4 sh = *(const float4*)&shift[cb];
    float4 o;
    o.x = sc.x * v.x + sh.x; o.x = o.x > 0.f ? o.x : NEG_ACT * o.x;
    o.y = sc.y * v.y + sh.y; o.y = o.y > 0.f ? o.y : NEG_ACT * o.y;
    o.z = sc.z * v.z + sh.z; o.z = o.z > 0.f ? o.z : NEG_ACT * o.z;
    o.w = sc.w * v.w + sh.w; o.w = o.w > 0.f ? o.w : NEG_ACT * o.w;
    if (RES) {
        float4 r = ((const float4*)Res)[i];
        o.x += r.x; o.y += r.y; o.z += r.z; o.w += r.w;
    }
    ((float4*)Out)[i] = o;
}

// ---------------- launch ----------------

extern "C" void kernel_launch(void* const* d_in, const int* in_sizes, int n_in,
                              void* d_out, int out_size, void* d_ws, size_t ws_size,
                              hipStream_t stream) {
    const float* x    = (const float*)d_in[0];
    const int*   ei   = (const int*)d_in[1];
    const float* W1   = (const float*)d_in[2];
    const float* a1s  = (const float*)d_in[3];
    const float* a1d  = (const float*)d_in[4];
    const float* b1   = (const float*)d_in[5];
    const float* W2   = (const float*)d_in[6];
    const float* a2s  = (const float*)d_in[7];
    const float* a2d  = (const float*)d_in[8];
    const float* b2   = (const float*)d_in[9];
    const float* W3   = (const float*)d_in[10];
    const float* a3s  = (const float*)d_in[11];
    const float* a3d  = (const float*)d_in[12];
    const float* b3   = (const float*)d_in[13];
    const float* gamma = (const float*)d_in[14];
    const float* beta  = (const float*)d_in[15];
    float* out = (float*)d_out;

    const int Nn = in_sizes[0] / 128;   // 50000
    const int E  = in_sizes[1] / 2;     // 400000
    const int Ep = E + Nn;              // with self loops

    size_t off = 0;
    char* base = (char*)d_ws;
    auto alloc = [&](size_t bytes) -> void* {
        void* p = base + off;
        off = (off + bytes + 255) & ~(size_t)255;
        return p;
    };
    float* bufA   = (float*)alloc((size_t)Nn * 256 * 4);  // GEMM out (h)
    float* bufB   = (float*)alloc((size_t)Nn * 256 * 4);  // aggregated y
    float* bufC   = (float*)alloc((size_t)Nn * 256 * 4);  // residual / layer input
    float* als    = (float*)alloc((size_t)Nn * 4 * 4);
    float* ald    = (float*)alloc((size_t)Nn * 4 * 4);
    int*   deg    = (int*)alloc((size_t)Nn * 4);
    int*   offs   = (int*)alloc((size_t)(Nn + 1) * 4);
    int*   cursor = (int*)alloc((size_t)Nn * 4);
    int*   bsum   = (int*)alloc(64 * 4);
    int*   csr    = (int*)alloc((size_t)Ep * 4);
    float* gsum   = (float*)alloc(256 * 4);
    float* gsq    = (float*)alloc(256 * 4);
    float* scale  = (float*)alloc(256 * 4);
    float* shift  = (float*)alloc(256 * 4);
    (void)ws_size;

    const int G = (Nn + SCAN_CHUNK - 1) / SCAN_CHUNK;  // 49

    // ---- CSR build (shared by all 3 layers) ----
    init_deg<<<(Nn + 255) / 256, 256, 0, stream>>>(deg, Nn);
    count_edges<<<(E + 255) / 256, 256, 0, stream>>>(ei, deg, E);
    scan1<<<G, 256, 0, stream>>>(deg, offs, bsum, Nn);
    scan2<<<1, 64, 0, stream>>>(bsum, G);
    scan3<<<(Nn + 255) / 256, 256, 0, stream>>>(offs, bsum, cursor, Nn, Ep);
    fill_csr<<<(Ep + 255) / 256, 256, 0, stream>>>(ei, cursor, csr, E, Nn);

    const int gm = (Nn + 63) / 64;
    const int nagg = (Nn + 3) / 4;
    const int total4 = Nn * 64;  // N*256/4
    const int napply = (total4 + 255) / 256;

    // ---- Layer 1: GATConv(128 -> 4x64) ----
    gemm_tn<128, 256><<<dim3(gm, 4), 256, 0, stream>>>(x, W1, bufA, Nn);
    compute_al<4><<<Nn, 256, 0, stream>>>(bufA, a1s, a1d, als, ald, Nn);
    aggregate_h4<<<nagg, 256, 0, stream>>>(bufA, als, ald, offs, csr, b1, bufB, Nn);
    zero_bn<<<1, 256, 0, stream>>>(gsum, gsq);
    bn_stats<<<256, 256, 0, stream>>>(bufB, gsum, gsq, Nn);
    bn_final<<<1, 256, 0, stream>>>(gsum, gsq, gamma, beta, scale, shift, Nn);
    bn_apply<false><<<napply, 256, 0, stream>>>(bufB, scale, shift, nullptr, bufC, total4);

    // ---- Layer 2: GATConv(256 -> 4x64) + residual ----
    gemm_tn<256, 256><<<dim3(gm, 4), 256, 0, stream>>>(bufC, W2, bufA, Nn);
    compute_al<4><<<Nn, 256, 0, stream>>>(bufA, a2s, a2d, als, ald, Nn);
    aggregate_h4<<<nagg, 256, 0, stream>>>(bufA, als, ald, offs, csr, b2, bufB, Nn);
    zero_bn<<<1, 256, 0, stream>>>(gsum, gsq);
    bn_stats<<<256, 256, 0, stream>>>(bufB, gsum, gsq, Nn);
    bn_final<<<1, 256, 0, stream>>>(gsum, gsq, gamma, beta, scale, shift, Nn);
    bn_apply<true><<<napply, 256, 0, stream>>>(bufB, scale, shift, bufC, bufC, total4);

    // ---- Layer 3: GATConv(256 -> 64, heads=1) ----
    gemm_tn<256, 64><<<dim3(gm, 1), 256, 0, stream>>>(bufC, W3, bufA, Nn);
    compute_al<1><<<Nn, 64, 0, stream>>>(bufA, a3s, a3d, als, ald, Nn);
    aggregate_h1<<<nagg, 256, 0, stream>>>(bufA, als, ald, offs, csr, b3, out, Nn);
}

// Round 2
// 631.142 us; speedup vs baseline: 1.1583x; 1.1583x over previous
//
#include <hip/hip_runtime.h>
#include <hip/hip_bf16.h>

#define NEG_ATT 0.2f
#define NEG_ACT 0.01f

typedef __attribute__((ext_vector_type(8))) short short8;
typedef __attribute__((ext_vector_type(4))) float f32x4;

__device__ __forceinline__ unsigned short f2bf(float f) {
    unsigned int u = __float_as_uint(f);
    unsigned int r = (u + 0x7fff + ((u >> 16) & 1)) >> 16;  // RNE
    return (unsigned short)r;
}

// ---------------- CSR build ----------------

__global__ void init_deg(int* deg, int Nn) {
    int t = blockIdx.x * 256 + threadIdx.x;
    if (t < Nn) deg[t] = 1;  // self loop
}

__global__ void count_edges(const int* __restrict__ ei, int* deg, int E) {
    int t = blockIdx.x * 256 + threadIdx.x;
    if (t < E) atomicAdd(&deg[ei[E + t]], 1);  // dst row
}

#define SCAN_CHUNK 1024
__global__ void scan1(const int* __restrict__ deg, int* __restrict__ offs,
                      int* blocksum, int Nn) {
    __shared__ int sh[256];
    int b = blockIdx.x, t = threadIdx.x;
    int base = b * SCAN_CHUNK + t * 4;
    int v[4];
    int s = 0;
    for (int j = 0; j < 4; j++) {
        int idx = base + j;
        v[j] = (idx < Nn) ? deg[idx] : 0;
        s += v[j];
    }
    sh[t] = s;
    __syncthreads();
    for (int off = 1; off < 256; off <<= 1) {
        int x = (t >= off) ? sh[t - off] : 0;
        __syncthreads();
        sh[t] += x;
        __syncthreads();
    }
    int excl = sh[t] - s;
    if (t == 255) blocksum[b] = sh[255];
    int run = excl;
    for (int j = 0; j < 4; j++) {
        int idx = base + j;
        if (idx < Nn) offs[idx] = run;
        run += v[j];
    }
}

__global__ void scan2(int* blocksum, int G) {
    if (threadIdx.x == 0 && blockIdx.x == 0) {
        int run = 0;
        for (int i = 0; i < G; i++) { int v = blocksum[i]; blocksum[i] = run; run += v; }
    }
}

__global__ void scan3(int* offs, const int* base, int* cursor, int Nn, int total) {
    int i = blockIdx.x * 256 + threadIdx.x;
    if (i < Nn) {
        int v = offs[i] + base[i >> 10];
        offs[i] = v;
        cursor[i] = v;
    }
    if (i == 0) offs[Nn] = total;
}

__global__ void fill_csr(const int* __restrict__ ei, int* cursor, int* csr, int E, int Nn) {
    int t = blockIdx.x * 256 + threadIdx.x;
    if (t < E) {
        int s = ei[t];
        int d = ei[E + t];
        int p = atomicAdd(&cursor[d], 1);
        csr[p] = s;
    } else if (t < E + Nn) {
        int nn = t - E;
        int p = atomicAdd(&cursor[nn], 1);
        csr[p] = nn;
    }
}

// ---------------- fp32 -> bf16 conversion (8 elems/thread) ----------------
// n and ntot are multiples of 8; region [n, ntot) is zero-filled padding.

__global__ __launch_bounds__(256) void f2b8(const float* __restrict__ in,
                                            unsigned short* __restrict__ out,
                                            int n, int ntot) {
    int i = (blockIdx.x * 256 + threadIdx.x) * 8;
    if (i >= ntot) return;
    ushort4 lo, hi;
    if (i < n) {
        float4 a = *(const float4*)&in[i];
        float4 b = *(const float4*)&in[i + 4];
        lo = make_ushort4(f2bf(a.x), f2bf(a.y), f2bf(a.z), f2bf(a.w));
        hi = make_ushort4(f2bf(b.x), f2bf(b.y), f2bf(b.z), f2bf(b.w));
    } else {
        lo = make_ushort4(0, 0, 0, 0);
        hi = lo;
    }
    *(ushort4*)&out[i] = lo;
    *(ushort4*)&out[i + 4] = hi;
}

// ---------------- MFMA GEMM (TN): C[m,n] = sum_k X[m,k] * W[n,k] ----------------
// Xb: [Mpad,K] bf16 row-major (pad rows zero). Wb: [CO,K] bf16 row-major.
// BM=128, BN=64, BK=64. 256 thr = 4 waves; wave w -> rows [w*32, w*32+32).

template <int K, int CO>
__global__ __launch_bounds__(256) void gemm_mfma(const unsigned short* __restrict__ Xb,
                                                 const unsigned short* __restrict__ Wb,
                                                 float* __restrict__ C) {
    constexpr int BM = 128, BN = 64, BK = 64, LD = 72;  // LD halfwords: 2-way-free banks
    __shared__ unsigned short As[BM * LD];
    __shared__ unsigned short Bs[BN * LD];
    int tid = threadIdx.x;
    int wave = tid >> 6, lane = tid & 63;
    int quad = lane >> 4, l16 = lane & 15;
    int m0 = blockIdx.x * BM, n0 = blockIdx.y * BN;
    int arow = tid >> 3;          // 0..31
    int achk = (tid & 7) * 8;     // halfword offset within row, 16B chunks
    f32x4 acc[2][4] = {};
    for (int k0 = 0; k0 < K; k0 += BK) {
        __syncthreads();
#pragma unroll
        for (int p = 0; p < 4; p++) {
            int r = arow + p * 32;
            *(int4*)&As[r * LD + achk] = *(const int4*)&Xb[(size_t)(m0 + r) * K + k0 + achk];
        }
#pragma unroll
        for (int p = 0; p < 2; p++) {
            int r = arow + p * 32;
            *(int4*)&Bs[r * LD + achk] = *(const int4*)&Wb[(size_t)(n0 + r) * K + k0 + achk];
        }
        __syncthreads();
#pragma unroll
        for (int ks = 0; ks < 2; ks++) {
            short8 af[2], bfr[4];
#pragma unroll
            for (int i = 0; i < 2; i++)
                af[i] = *(const short8*)&As[(wave * 32 + i * 16 + l16) * LD + ks * 32 + quad * 8];
#pragma unroll
            for (int j = 0; j < 4; j++)
                bfr[j] = *(const short8*)&Bs[(j * 16 + l16) * LD + ks * 32 + quad * 8];
#pragma unroll
            for (int i = 0; i < 2; i++)
#pragma unroll
                for (int j = 0; j < 4; j++)
                    acc[i][j] = __builtin_amdgcn_mfma_f32_16x16x32_bf16(af[i], bfr[j], acc[i][j], 0, 0, 0);
        }
    }
    // C/D layout: col = lane&15, row = quad*4 + reg
#pragma unroll
    for (int i = 0; i < 2; i++)
#pragma unroll
        for (int r = 0; r < 4; r++) {
            int m = m0 + wave * 32 + i * 16 + quad * 4 + r;
#pragma unroll
            for (int j = 0; j < 4; j++)
                C[(size_t)m * CO + n0 + j * 16 + l16] = acc[i][j][r];
        }
}

// ---------------- attention logits per node ----------------

template <int HEADS>
__global__ void compute_al(const float* __restrict__ Hmat, const float* __restrict__ a_s,
                           const float* __restrict__ a_d, float* als, float* ald, int Nn) {
    int n = blockIdx.x;
    int hd = threadIdx.x >> 6;
    int lane = threadIdx.x & 63;
    float v = Hmat[(size_t)n * (HEADS * 64) + hd * 64 + lane];
    float ps = v * a_s[hd * 64 + lane];
    float pd = v * a_d[hd * 64 + lane];
    for (int off = 32; off; off >>= 1) {
        ps += __shfl_down(ps, off);
        pd += __shfl_down(pd, off);
    }
    if (lane == 0) {
        als[n * HEADS + hd] = ps;
        ald[n * HEADS + hd] = pd;
    }
}

// ---------------- edge-softmax aggregation (one wave per node) ----------------

__global__ __launch_bounds__(256) void aggregate_h4(
    const float* __restrict__ Hmat, const float* __restrict__ als,
    const float* __restrict__ ald, const int* __restrict__ offs,
    const int* __restrict__ csr, const float* __restrict__ bias,
    float* __restrict__ Yout, int Nn) {
    int wave = threadIdx.x >> 6;
    int lane = threadIdx.x & 63;
    int n = blockIdx.x * 4 + wave;
    if (n >= Nn) return;
    int hd = lane >> 4;
    int c4 = lane * 4;
    float aldn = ald[n * 4 + hd];
    int beg = offs[n], end = offs[n + 1];
    float4 acc = make_float4(0.f, 0.f, 0.f, 0.f);
    float den = 0.f;
    for (int i = beg; i < end; i++) {
        int s = csr[i];
        float e = als[s * 4 + hd] + aldn;
        e = e > 0.f ? e : NEG_ATT * e;
        float w = __expf(e);
        den += w;
        float4 hv = *(const float4*)&Hmat[(size_t)s * 256 + c4];
        acc.x += w * hv.x; acc.y += w * hv.y;
        acc.z += w * hv.z; acc.w += w * hv.w;
    }
    float inv = 1.f / den;
    float4 bv = *(const float4*)&bias[c4];
    float4 o = make_float4(acc.x * inv + bv.x, acc.y * inv + bv.y,
                           acc.z * inv + bv.z, acc.w * inv + bv.w);
    *(float4*)&Yout[(size_t)n * 256 + c4] = o;
}

__global__ __launch_bounds__(256) void aggregate_h1(
    const float* __restrict__ Hmat, const float* __restrict__ als,
    const float* __restrict__ ald, const int* __restrict__ offs,
    const int* __restrict__ csr, const float* __restrict__ bias,
    float* __restrict__ Yout, int Nn) {
    int wave = threadIdx.x >> 6;
    int lane = threadIdx.x & 63;
    int n = blockIdx.x * 4 + wave;
    if (n >= Nn) return;
    float aldn = ald[n];
    int beg = offs[n], end = offs[n + 1];
    float acc = 0.f, den = 0.f;
    for (int i = beg; i < end; i++) {
        int s = csr[i];
        float e = als[s] + aldn;
        e = e > 0.f ? e : NEG_ATT * e;
        float w = __expf(e);
        den += w;
        acc += w * Hmat[(size_t)s * 64 + lane];
    }
    Yout[(size_t)n * 64 + lane] = acc / den + bias[lane];
}

// ---------------- BatchNorm (training-mode, biased var) ----------------

__global__ void zero_bn(float* gsum, float* gsq) {
    gsum[threadIdx.x] = 0.f;
    gsq[threadIdx.x] = 0.f;
}

__global__ __launch_bounds__(256) void bn_stats(const float* __restrict__ Y,
                                                float* gsum, float* gsq, int Nn) {
    int ch = threadIdx.x;
    int rows_per = (Nn + gridDim.x - 1) / gridDim.x;
    int r0 = blockIdx.x * rows_per;
    int r1 = r0 + rows_per;
    if (r1 > Nn) r1 = Nn;
    float s = 0.f, q = 0.f;
    for (int r = r0; r < r1; r++) {
        float v = Y[(size_t)r * 256 + ch];
        s += v;
        q += v * v;
    }
    atomicAdd(&gsum[ch], s);
    atomicAdd(&gsq[ch], q);
}

__global__ void bn_final(const float* gsum, const float* gsq, const float* __restrict__ gamma,
                         const float* __restrict__ beta, float* scale, float* shift, int Nn) {
    int ch = threadIdx.x;
    float inv_n = 1.f / (float)Nn;
    float mu = gsum[ch] * inv_n;
    float var = gsq[ch] * inv_n - mu * mu;
    float sc = gamma[ch] * rsqrtf(var + 1e-5f);
    scale[ch] = sc;
    shift[ch] = beta[ch] - mu * sc;
}

// Writes fp32 Out (for residual chain) AND a bf16 copy (next GEMM input).
// Region [total4, total4pad) zero-fills only the bf16 buffer (GEMM pad rows).
template <bool RES>
__global__ __launch_bounds__(256) void bn_apply(const float* __restrict__ Y,
                                                const float* __restrict__ scale,
                                                const float* __restrict__ shift,
                                                const float* __restrict__ Res,
                                                float* __restrict__ Out,
                                                unsigned short* __restrict__ OutB,
                                                int total4, int total4pad) {
    int i = blockIdx.x * 256 + threadIdx.x;
    if (i >= total4pad) return;
    if (i >= total4) {
        *(ushort4*)&OutB[i * 4] = make_ushort4(0, 0, 0, 0);
        return;
    }
    float4 v = ((const float4*)Y)[i];
    int cb = (i * 4) & 255;
    float4 sc = *(const float4*)&scale[cb];
    float4 sh = *(const float4*)&shift[cb];
    float4 o;
    o.x = sc.x * v.x + sh.x; o.x = o.x > 0.f ? o.x : NEG_ACT * o.x;
    o.y = sc.y * v.y + sh.y; o.y = o.y > 0.f ? o.y : NEG_ACT * o.y;
    o.z = sc.z * v.z + sh.z; o.z = o.z > 0.f ? o.z : NEG_ACT * o.z;
    o.w = sc.w * v.w + sh.w; o.w = o.w > 0.f ? o.w : NEG_ACT * o.w;
    if (RES) {
        float4 r = ((const float4*)Res)[i];
        o.x += r.x; o.y += r.y; o.z += r.z; o.w += r.w;
    }
    ((float4*)Out)[i] = o;
    *(ushort4*)&OutB[i * 4] = make_ushort4(f2bf(o.x), f2bf(o.y), f2bf(o.z), f2bf(o.w));
}

// ---------------- launch ----------------

extern "C" void kernel_launch(void* const* d_in, const int* in_sizes, int n_in,
                              void* d_out, int out_size, void* d_ws, size_t ws_size,
                              hipStream_t stream) {
    const float* x    = (const float*)d_in[0];
    const int*   ei   = (const int*)d_in[1];
    const float* W1   = (const float*)d_in[2];
    const float* a1s  = (const float*)d_in[3];
    const float* a1d  = (const float*)d_in[4];
    const float* b1   = (const float*)d_in[5];
    const float* W2   = (const float*)d_in[6];
    const float* a2s  = (const float*)d_in[7];
    const float* a2d  = (const float*)d_in[8];
    const float* b2   = (const float*)d_in[9];
    const float* W3   = (const float*)d_in[10];
    const float* a3s  = (const float*)d_in[11];
    const float* a3d  = (const float*)d_in[12];
    const float* b3   = (const float*)d_in[13];
    const float* gamma = (const float*)d_in[14];
    const float* beta  = (const float*)d_in[15];
    float* out = (float*)d_out;

    const int Nn = in_sizes[0] / 128;   // 50000
    const int E  = in_sizes[1] / 2;     // 400000
    const int Ep = E + Nn;
    const int Mpad = (Nn + 127) & ~127; // 50048

    size_t off = 0;
    char* base = (char*)d_ws;
    auto alloc = [&](size_t bytes) -> void* {
        void* p = base + off;
        off = (off + bytes + 255) & ~(size_t)255;
        return p;
    };
    float* bufA   = (float*)alloc((size_t)Mpad * 256 * 4);  // GEMM out (h)
    float* bufB   = (float*)alloc((size_t)Nn * 256 * 4);    // aggregated y
    float* bufC   = (float*)alloc((size_t)Nn * 256 * 4);    // residual / fp32 layer input
    unsigned short* xb1  = (unsigned short*)alloc((size_t)Mpad * 128 * 2);  // bf16 x
    unsigned short* xbig = (unsigned short*)alloc((size_t)Mpad * 256 * 2);  // bf16 layer2/3 in
    unsigned short* wb1  = (unsigned short*)alloc((size_t)256 * 128 * 2);
    unsigned short* wb2  = (unsigned short*)alloc((size_t)256 * 256 * 2);
    unsigned short* wb3  = (unsigned short*)alloc((size_t)64 * 256 * 2);
    float* als    = (float*)alloc((size_t)Nn * 4 * 4);
    float* ald    = (float*)alloc((size_t)Nn * 4 * 4);
    int*   deg    = (int*)alloc((size_t)Nn * 4);
    int*   offs   = (int*)alloc((size_t)(Nn + 1) * 4);
    int*   cursor = (int*)alloc((size_t)Nn * 4);
    int*   bsum   = (int*)alloc(64 * 4);
    int*   csr    = (int*)alloc((size_t)Ep * 4);
    float* gsum   = (float*)alloc(256 * 4);
    float* gsq    = (float*)alloc(256 * 4);
    float* scale  = (float*)alloc(256 * 4);
    float* shift  = (float*)alloc(256 * 4);
    (void)ws_size;

    const int G = (Nn + SCAN_CHUNK - 1) / SCAN_CHUNK;

    // ---- CSR build (shared by all 3 layers) ----
    init_deg<<<(Nn + 255) / 256, 256, 0, stream>>>(deg, Nn);
    count_edges<<<(E + 255) / 256, 256, 0, stream>>>(ei, deg, E);
    scan1<<<G, 256, 0, stream>>>(deg, offs, bsum, Nn);
    scan2<<<1, 64, 0, stream>>>(bsum, G);
    scan3<<<(Nn + 255) / 256, 256, 0, stream>>>(offs, bsum, cursor, Nn, Ep);
    fill_csr<<<(Ep + 255) / 256, 256, 0, stream>>>(ei, cursor, csr, E, Nn);

    // ---- bf16 conversions ----
    {
        int ntot = Mpad * 128;
        f2b8<<<(ntot / 8 + 255) / 256, 256, 0, stream>>>(x, xb1, Nn * 128, ntot);
        f2b8<<<(256 * 128 / 8 + 255) / 256, 256, 0, stream>>>(W1, wb1, 256 * 128, 256 * 128);
        f2b8<<<(256 * 256 / 8 + 255) / 256, 256, 0, stream>>>(W2, wb2, 256 * 256, 256 * 256);
        f2b8<<<(64 * 256 / 8 + 255) / 256, 256, 0, stream>>>(W3, wb3, 64 * 256, 64 * 256);
    }

    const int gm = Mpad / 128;               // 391
    const int nagg = (Nn + 3) / 4;
    const int total4 = Nn * 64;              // fp32 float4 count
    const int total4pad = Mpad * 64;
    const int napply = (total4pad + 255) / 256;

    // ---- Layer 1: GATConv(128 -> 4x64) ----
    gemm_mfma<128, 256><<<dim3(gm, 4), 256, 0, stream>>>(xb1, wb1, bufA);
    compute_al<4><<<Nn, 256, 0, stream>>>(bufA, a1s, a1d, als, ald, Nn);
    aggregate_h4<<<nagg, 256, 0, stream>>>(bufA, als, ald, offs, csr, b1, bufB, Nn);
    zero_bn<<<1, 256, 0, stream>>>(gsum, gsq);
    bn_stats<<<256, 256, 0, stream>>>(bufB, gsum, gsq, Nn);
    bn_final<<<1, 256, 0, stream>>>(gsum, gsq, gamma, beta, scale, shift, Nn);
    bn_apply<false><<<napply, 256, 0, stream>>>(bufB, scale, shift, nullptr, bufC, xbig,
                                                total4, total4pad);

    // ---- Layer 2: GATConv(256 -> 4x64) + residual ----
    gemm_mfma<256, 256><<<dim3(gm, 4), 256, 0, stream>>>(xbig, wb2, bufA);
    compute_al<4><<<Nn, 256, 0, stream>>>(bufA, a2s, a2d, als, ald, Nn);
    aggregate_h4<<<nagg, 256, 0, stream>>>(bufA, als, ald, offs, csr, b2, bufB, Nn);
    zero_bn<<<1, 256, 0, stream>>>(gsum, gsq);
    bn_stats<<<256, 256, 0, stream>>>(bufB, gsum, gsq, Nn);
    bn_final<<<1, 256, 0, stream>>>(gsum, gsq, gamma, beta, scale, shift, Nn);
    bn_apply<true><<<napply, 256, 0, stream>>>(bufB, scale, shift, bufC, bufC, xbig,
                                               total4, total4pad);

    // ---- Layer 3: GATConv(256 -> 64, heads=1) ----
    gemm_mfma<256, 64><<<dim3(gm, 1), 256, 0, stream>>>(xbig, wb3, bufA);
    compute_al<1><<<Nn, 64, 0, stream>>>(bufA, a3s, a3d, als, ald, Nn);
    aggregate_h1<<<nagg, 256, 0, stream>>>(bufA, als, ald, offs, csr, b3, out, Nn);
}

// Round 3
// 507.515 us; speedup vs baseline: 1.4405x; 1.2436x over previous
//
#include <hip/hip_runtime.h>
#include <hip/hip_bf16.h>

#define NEG_ATT 0.2f
#define NEG_ACT 0.01f

typedef __attribute__((ext_vector_type(8))) short short8;
typedef __attribute__((ext_vector_type(4))) float f32x4;

__device__ __forceinline__ unsigned short f2bf(float f) {
    unsigned int u = __float_as_uint(f);
    unsigned int r = (u + 0x7fff + ((u >> 16) & 1)) >> 16;  // RNE
    return (unsigned short)r;
}
__device__ __forceinline__ float b2f(unsigned short h) {
    return __uint_as_float((unsigned int)h << 16);
}

// ---------------- CSR build ----------------

__global__ void init_deg(int* deg, int Nn) {
    int t = blockIdx.x * 256 + threadIdx.x;
    if (t < Nn) deg[t] = 1;  // self loop
}

__global__ void count_edges(const int* __restrict__ ei, int* deg, int E) {
    int t = blockIdx.x * 256 + threadIdx.x;
    if (t < E) atomicAdd(&deg[ei[E + t]], 1);  // dst row
}

#define SCAN_CHUNK 1024
__global__ void scan1(const int* __restrict__ deg, int* __restrict__ offs,
                      int* blocksum, int Nn) {
    __shared__ int sh[256];
    int b = blockIdx.x, t = threadIdx.x;
    int base = b * SCAN_CHUNK + t * 4;
    int v[4];
    int s = 0;
    for (int j = 0; j < 4; j++) {
        int idx = base + j;
        v[j] = (idx < Nn) ? deg[idx] : 0;
        s += v[j];
    }
    sh[t] = s;
    __syncthreads();
    for (int off = 1; off < 256; off <<= 1) {
        int x = (t >= off) ? sh[t - off] : 0;
        __syncthreads();
        sh[t] += x;
        __syncthreads();
    }
    int excl = sh[t] - s;
    if (t == 255) blocksum[b] = sh[255];
    int run = excl;
    for (int j = 0; j < 4; j++) {
        int idx = base + j;
        if (idx < Nn) offs[idx] = run;
        run += v[j];
    }
}

__global__ void scan2(int* blocksum, int G) {
    if (threadIdx.x == 0 && blockIdx.x == 0) {
        int run = 0;
        for (int i = 0; i < G; i++) { int v = blocksum[i]; blocksum[i] = run; run += v; }
    }
}

__global__ void scan3(int* offs, const int* base, int* cursor, int Nn, int total) {
    int i = blockIdx.x * 256 + threadIdx.x;
    if (i < Nn) {
        int v = offs[i] + base[i >> 10];
        offs[i] = v;
        cursor[i] = v;
    }
    if (i == 0) offs[Nn] = total;
}

__global__ void fill_csr(const int* __restrict__ ei, int* cursor, int* csr, int E, int Nn) {
    int t = blockIdx.x * 256 + threadIdx.x;
    if (t < E) {
        int s = ei[t];
        int d = ei[E + t];
        int p = atomicAdd(&cursor[d], 1);
        csr[p] = s;
    } else if (t < E + Nn) {
        int nn = t - E;
        int p = atomicAdd(&cursor[nn], 1);
        csr[p] = nn;
    }
}

// ---------------- fp32 -> bf16 conversion ----------------

__global__ __launch_bounds__(256) void f2b8(const float* __restrict__ in,
                                            unsigned short* __restrict__ out,
                                            int n, int ntot) {
    int i = (blockIdx.x * 256 + threadIdx.x) * 8;
    if (i >= ntot) return;
    ushort4 lo, hi;
    if (i < n) {
        float4 a = *(const float4*)&in[i];
        float4 b = *(const float4*)&in[i + 4];
        lo = make_ushort4(f2bf(a.x), f2bf(a.y), f2bf(a.z), f2bf(a.w));
        hi = make_ushort4(f2bf(b.x), f2bf(b.y), f2bf(b.z), f2bf(b.w));
    } else {
        lo = make_ushort4(0, 0, 0, 0);
        hi = lo;
    }
    *(ushort4*)&out[i] = lo;
    *(ushort4*)&out[i + 4] = hi;
}

// ---------------- MFMA GEMM (TN) + fused attention-logit epilogue ----------------
// Xb: [Mpad,K] bf16 (pad rows zero). Wb: [CO,K] bf16. Hb out: [Mpad,CO] bf16.
// blockIdx.y = head (BN=64 == one head's channels). als/ald: [Mpad,HEADS] fp32.

template <int K, int CO, int HEADS>
__global__ __launch_bounds__(256) void gemm_mfma(
    const unsigned short* __restrict__ Xb, const unsigned short* __restrict__ Wb,
    unsigned short* __restrict__ Hb, const float* __restrict__ a_s,
    const float* __restrict__ a_d, float* __restrict__ als, float* __restrict__ ald) {
    constexpr int BM = 128, BN = 64, BK = 64, LD = 72, SLD = 68;
    __shared__ __align__(16) char smem[4 * 32 * SLD * 4];  // 34816 B (>= As+Bs 27648 B)
    unsigned short* As = (unsigned short*)smem;
    unsigned short* Bs = As + BM * LD;
    int tid = threadIdx.x;
    int wave = tid >> 6, lane = tid & 63;
    int quad = lane >> 4, l16 = lane & 15;
    int m0 = blockIdx.x * BM, n0 = blockIdx.y * BN;
    int hd = blockIdx.y;
    int arow = tid >> 3;
    int achk = (tid & 7) * 8;
    f32x4 acc[2][4] = {};
    for (int k0 = 0; k0 < K; k0 += BK) {
        __syncthreads();
#pragma unroll
        for (int p = 0; p < 4; p++) {
            int r = arow + p * 32;
            *(int4*)&As[r * LD + achk] = *(const int4*)&Xb[(size_t)(m0 + r) * K + k0 + achk];
        }
#pragma unroll
        for (int p = 0; p < 2; p++) {
            int r = arow + p * 32;
            *(int4*)&Bs[r * LD + achk] = *(const int4*)&Wb[(size_t)(n0 + r) * K + k0 + achk];
        }
        __syncthreads();
#pragma unroll
        for (int ks = 0; ks < 2; ks++) {
            short8 af[2], bfr[4];
#pragma unroll
            for (int i = 0; i < 2; i++)
                af[i] = *(const short8*)&As[(wave * 32 + i * 16 + l16) * LD + ks * 32 + quad * 8];
#pragma unroll
            for (int j = 0; j < 4; j++)
                bfr[j] = *(const short8*)&Bs[(j * 16 + l16) * LD + ks * 32 + quad * 8];
#pragma unroll
            for (int i = 0; i < 2; i++)
#pragma unroll
                for (int j = 0; j < 4; j++)
                    acc[i][j] = __builtin_amdgcn_mfma_f32_16x16x32_bf16(af[i], bfr[j], acc[i][j], 0, 0, 0);
        }
    }
    __syncthreads();  // all waves done with As/Bs before reusing smem as staging

    // ---- fused attention logits: als/ald[m] = sum_c h[m,c]*a[c] over this head ----
    float asv[4], adv[4];
#pragma unroll
    for (int j = 0; j < 4; j++) {
        asv[j] = a_s[hd * 64 + j * 16 + l16];
        adv[j] = a_d[hd * 64 + j * 16 + l16];
    }
#pragma unroll
    for (int i = 0; i < 2; i++)
#pragma unroll
        for (int r = 0; r < 4; r++) {
            float ps = acc[i][0][r] * asv[0] + acc[i][1][r] * asv[1] +
                       acc[i][2][r] * asv[2] + acc[i][3][r] * asv[3];
            float pd = acc[i][0][r] * adv[0] + acc[i][1][r] * adv[1] +
                       acc[i][2][r] * adv[2] + acc[i][3][r] * adv[3];
#pragma unroll
            for (int mm = 1; mm < 16; mm <<= 1) {
                ps += __shfl_xor(ps, mm);
                pd += __shfl_xor(pd, mm);
            }
            if (l16 == 0) {
                int m = m0 + wave * 32 + i * 16 + quad * 4 + r;
                als[m * HEADS + hd] = ps;
                ald[m * HEADS + hd] = pd;
            }
        }

    // ---- stage C through LDS (per-wave private region), store as bf16 ----
    float* stg = (float*)smem + wave * 32 * SLD;
#pragma unroll
    for (int i = 0; i < 2; i++)
#pragma unroll
        for (int j = 0; j < 4; j++)
#pragma unroll
            for (int r = 0; r < 4; r++)
                stg[(i * 16 + quad * 4 + r) * SLD + j * 16 + l16] = acc[i][j][r];
    int g = lane >> 3, c8 = (lane & 7) * 8;
#pragma unroll
    for (int p = 0; p < 4; p++) {
        int row = p * 8 + g;
        float4 v0 = *(const float4*)&stg[row * SLD + c8];
        float4 v1 = *(const float4*)&stg[row * SLD + c8 + 4];
        uint4 o;
        o.x = ((unsigned)f2bf(v0.y) << 16) | f2bf(v0.x);
        o.y = ((unsigned)f2bf(v0.w) << 16) | f2bf(v0.z);
        o.z = ((unsigned)f2bf(v1.y) << 16) | f2bf(v1.x);
        o.w = ((unsigned)f2bf(v1.w) << 16) | f2bf(v1.z);
        *(uint4*)&Hb[(size_t)(m0 + wave * 32 + row) * CO + n0 + c8] = o;
    }
}

// ---------------- edge-softmax aggregation (bf16 gather) ----------------

__global__ __launch_bounds__(256) void aggregate_h4(
    const unsigned short* __restrict__ Hb, const float* __restrict__ als,
    const float* __restrict__ ald, const int* __restrict__ offs,
    const int* __restrict__ csr, const float* __restrict__ bias,
    float* __restrict__ Yout, int Nn) {
    int wave = threadIdx.x >> 6;
    int lane = threadIdx.x & 63;
    int n = blockIdx.x * 4 + wave;
    if (n >= Nn) return;
    int hd = lane >> 4;
    int c4 = lane * 4;
    float aldn = ald[n * 4 + hd];
    int beg = offs[n], end = offs[n + 1];
    float4 acc = make_float4(0.f, 0.f, 0.f, 0.f);
    float den = 0.f;
    for (int i = beg; i < end; i++) {
        int s = csr[i];
        float e = als[s * 4 + hd] + aldn;
        e = e > 0.f ? e : NEG_ATT * e;
        float w = __expf(e);
        den += w;
        ushort4 hv = *(const ushort4*)&Hb[(size_t)s * 256 + c4];
        acc.x += w * b2f(hv.x); acc.y += w * b2f(hv.y);
        acc.z += w * b2f(hv.z); acc.w += w * b2f(hv.w);
    }
    float inv = 1.f / den;
    float4 bv = *(const float4*)&bias[c4];
    float4 o = make_float4(acc.x * inv + bv.x, acc.y * inv + bv.y,
                           acc.z * inv + bv.z, acc.w * inv + bv.w);
    *(float4*)&Yout[(size_t)n * 256 + c4] = o;
}

// heads=1, 64 channels: 4 nodes per wave, 16 lanes x 4ch each. Writes final out.
__global__ __launch_bounds__(256) void aggregate_h1(
    const unsigned short* __restrict__ Hb, const float* __restrict__ als,
    const float* __restrict__ ald, const int* __restrict__ offs,
    const int* __restrict__ csr, const float* __restrict__ bias,
    float* __restrict__ Yout, int Nn) {
    int wave = threadIdx.x >> 6;
    int lane = threadIdx.x & 63;
    int sub = lane >> 4, lane16 = lane & 15;
    int n = blockIdx.x * 16 + wave * 4 + sub;
    if (n >= Nn) return;
    int c4 = lane16 * 4;
    float aldn = ald[n];
    int beg = offs[n], end = offs[n + 1];
    float4 acc = make_float4(0.f, 0.f, 0.f, 0.f);
    float den = 0.f;
    for (int i = beg; i < end; i++) {
        int s = csr[i];
        float e = als[s] + aldn;
        e = e > 0.f ? e : NEG_ATT * e;
        float w = __expf(e);
        den += w;
        ushort4 hv = *(const ushort4*)&Hb[(size_t)s * 64 + c4];
        acc.x += w * b2f(hv.x); acc.y += w * b2f(hv.y);
        acc.z += w * b2f(hv.z); acc.w += w * b2f(hv.w);
    }
    float inv = 1.f / den;
    float4 bv = *(const float4*)&bias[c4];
    float4 o = make_float4(acc.x * inv + bv.x, acc.y * inv + bv.y,
                           acc.z * inv + bv.z, acc.w * inv + bv.w);
    *(float4*)&Yout[(size_t)n * 64 + c4] = o;
}

// ---------------- BatchNorm (training-mode, biased var) ----------------

__global__ void zero_bn(float* gsum, float* gsq) {
    gsum[threadIdx.x] = 0.f;
    gsq[threadIdx.x] = 0.f;
}

__global__ __launch_bounds__(256) void bn_stats(const float* __restrict__ Y,
                                                float* gsum, float* gsq, int Nn) {
    int ch = threadIdx.x;
    int rows_per = (Nn + gridDim.x - 1) / gridDim.x;
    int r0 = blockIdx.x * rows_per;
    int r1 = r0 + rows_per;
    if (r1 > Nn) r1 = Nn;
    float s = 0.f, q = 0.f;
    for (int r = r0; r < r1; r++) {
        float v = Y[(size_t)r * 256 + ch];
        s += v;
        q += v * v;
    }
    atomicAdd(&gsum[ch], s);
    atomicAdd(&gsq[ch], q);
}

__global__ void bn_final(const float* gsum, const float* gsq, const float* __restrict__ gamma,
                         const float* __restrict__ beta, float* scale, float* shift, int Nn) {
    int ch = threadIdx.x;
    float inv_n = 1.f / (float)Nn;
    float mu = gsum[ch] * inv_n;
    float var = gsq[ch] * inv_n - mu * mu;
    float sc = gamma[ch] * rsqrtf(var + 1e-5f);
    scale[ch] = sc;
    shift[ch] = beta[ch] - mu * sc;
}

// fp32 Out (residual chain) only when WF32; always writes bf16 OutB (next GEMM in).
template <bool RES, bool WF32>
__global__ __launch_bounds__(256) void bn_apply(const float* __restrict__ Y,
                                                const float* __restrict__ scale,
                                                const float* __restrict__ shift,
                                                const float* __restrict__ Res,
                                                float* __restrict__ Out,
                                                unsigned short* __restrict__ OutB,
                                                int total4, int total4pad) {
    int i = blockIdx.x * 256 + threadIdx.x;
    if (i >= total4pad) return;
    if (i >= total4) {
        *(ushort4*)&OutB[i * 4] = make_ushort4(0, 0, 0, 0);
        return;
    }
    float4 v = ((const float4*)Y)[i];
    int cb = (i * 4) & 255;
    float4 sc = *(const float4*)&scale[cb];
    float4 sh = *(const float4*)&shift[cb];
    float4 o;
    o.x = sc.x * v.x + sh.x; o.x = o.x > 0.f ? o.x : NEG_ACT * o.x;
    o.y = sc.y * v.y + sh.y; o.y = o.y > 0.f ? o.y : NEG_ACT * o.y;
    o.z = sc.z * v.z + sh.z; o.z = o.z > 0.f ? o.z : NEG_ACT * o.z;
    o.w = sc.w * v.w + sh.w; o.w = o.w > 0.f ? o.w : NEG_ACT * o.w;
    if (RES) {
        float4 r = ((const float4*)Res)[i];
        o.x += r.x; o.y += r.y; o.z += r.z; o.w += r.w;
    }
    if (WF32) ((float4*)Out)[i] = o;
    *(ushort4*)&OutB[i * 4] = make_ushort4(f2bf(o.x), f2bf(o.y), f2bf(o.z), f2bf(o.w));
}

// ---------------- launch ----------------

extern "C" void kernel_launch(void* const* d_in, const int* in_sizes, int n_in,
                              void* d_out, int out_size, void* d_ws, size_t ws_size,
                              hipStream_t stream) {
    const float* x    = (const float*)d_in[0];
    const int*   ei   = (const int*)d_in[1];
    const float* W1   = (const float*)d_in[2];
    const float* a1s  = (const float*)d_in[3];
    const float* a1d  = (const float*)d_in[4];
    const float* b1   = (const float*)d_in[5];
    const float* W2   = (const float*)d_in[6];
    const float* a2s  = (const float*)d_in[7];
    const float* a2d  = (const float*)d_in[8];
    const float* b2   = (const float*)d_in[9];
    const float* W3   = (const float*)d_in[10];
    const float* a3s  = (const float*)d_in[11];
    const float* a3d  = (const float*)d_in[12];
    const float* b3   = (const float*)d_in[13];
    const float* gamma = (const float*)d_in[14];
    const float* beta  = (const float*)d_in[15];
    float* out = (float*)d_out;

    const int Nn = in_sizes[0] / 128;   // 50000
    const int E  = in_sizes[1] / 2;     // 400000
    const int Ep = E + Nn;
    const int Mpad = (Nn + 127) & ~127; // 50048

    size_t off = 0;
    char* base = (char*)d_ws;
    auto alloc = [&](size_t bytes) -> void* {
        void* p = base + off;
        off = (off + bytes + 255) & ~(size_t)255;
        return p;
    };
    unsigned short* Hb   = (unsigned short*)alloc((size_t)Mpad * 256 * 2);  // bf16 h
    float* bufB   = (float*)alloc((size_t)Nn * 256 * 4);    // aggregated y (fp32)
    float* bufC   = (float*)alloc((size_t)Nn * 256 * 4);    // residual fp32
    unsigned short* xb1  = (unsigned short*)alloc((size_t)Mpad * 128 * 2);
    unsigned short* xbig = (unsigned short*)alloc((size_t)Mpad * 256 * 2);
    unsigned short* wb1  = (unsigned short*)alloc((size_t)256 * 128 * 2);
    unsigned short* wb2  = (unsigned short*)alloc((size_t)256 * 256 * 2);
    unsigned short* wb3  = (unsigned short*)alloc((size_t)64 * 256 * 2);
    float* als    = (float*)alloc((size_t)Mpad * 4 * 4);
    float* ald    = (float*)alloc((size_t)Mpad * 4 * 4);
    int*   deg    = (int*)alloc((size_t)Nn * 4);
    int*   offs   = (int*)alloc((size_t)(Nn + 1) * 4);
    int*   cursor = (int*)alloc((size_t)Nn * 4);
    int*   bsum   = (int*)alloc(64 * 4);
    int*   csr    = (int*)alloc((size_t)Ep * 4);
    float* gsum   = (float*)alloc(256 * 4);
    float* gsq    = (float*)alloc(256 * 4);
    float* scale  = (float*)alloc(256 * 4);
    float* shift  = (float*)alloc(256 * 4);
    (void)ws_size;

    const int G = (Nn + SCAN_CHUNK - 1) / SCAN_CHUNK;

    // ---- CSR build (shared by all 3 layers) ----
    init_deg<<<(Nn + 255) / 256, 256, 0, stream>>>(deg, Nn);
    count_edges<<<(E + 255) / 256, 256, 0, stream>>>(ei, deg, E);
    scan1<<<G, 256, 0, stream>>>(deg, offs, bsum, Nn);
    scan2<<<1, 64, 0, stream>>>(bsum, G);
    scan3<<<(Nn + 255) / 256, 256, 0, stream>>>(offs, bsum, cursor, Nn, Ep);
    fill_csr<<<(Ep + 255) / 256, 256, 0, stream>>>(ei, cursor, csr, E, Nn);

    // ---- bf16 conversions ----
    {
        int ntot = Mpad * 128;
        f2b8<<<(ntot / 8 + 255) / 256, 256, 0, stream>>>(x, xb1, Nn * 128, ntot);
        f2b8<<<(256 * 128 / 8 + 255) / 256, 256, 0, stream>>>(W1, wb1, 256 * 128, 256 * 128);
        f2b8<<<(256 * 256 / 8 + 255) / 256, 256, 0, stream>>>(W2, wb2, 256 * 256, 256 * 256);
        f2b8<<<(64 * 256 / 8 + 255) / 256, 256, 0, stream>>>(W3, wb3, 64 * 256, 64 * 256);
    }

    const int gm = Mpad / 128;
    const int nagg4 = (Nn + 3) / 4;
    const int nagg1 = (Nn + 15) / 16;
    const int total4 = Nn * 64;
    const int total4pad = Mpad * 64;
    const int napply = (total4pad + 255) / 256;

    // ---- Layer 1: GATConv(128 -> 4x64) ----
    gemm_mfma<128, 256, 4><<<dim3(gm, 4), 256, 0, stream>>>(xb1, wb1, Hb, a1s, a1d, als, ald);
    aggregate_h4<<<nagg4, 256, 0, stream>>>(Hb, als, ald, offs, csr, b1, bufB, Nn);
    zero_bn<<<1, 256, 0, stream>>>(gsum, gsq);
    bn_stats<<<256, 256, 0, stream>>>(bufB, gsum, gsq, Nn);
    bn_final<<<1, 256, 0, stream>>>(gsum, gsq, gamma, beta, scale, shift, Nn);
    bn_apply<false, true><<<napply, 256, 0, stream>>>(bufB, scale, shift, nullptr, bufC, xbig,
                                                      total4, total4pad);

    // ---- Layer 2: GATConv(256 -> 4x64) + residual ----
    gemm_mfma<256, 256, 4><<<dim3(gm, 4), 256, 0, stream>>>(xbig, wb2, Hb, a2s, a2d, als, ald);
    aggregate_h4<<<nagg4, 256, 0, stream>>>(Hb, als, ald, offs, csr, b2, bufB, Nn);
    zero_bn<<<1, 256, 0, stream>>>(gsum, gsq);
    bn_stats<<<256, 256, 0, stream>>>(bufB, gsum, gsq, Nn);
    bn_final<<<1, 256, 0, stream>>>(gsum, gsq, gamma, beta, scale, shift, Nn);
    bn_apply<true, false><<<napply, 256, 0, stream>>>(bufB, scale, shift, bufC, nullptr, xbig,
                                                      total4, total4pad);

    // ---- Layer 3: GATConv(256 -> 64, heads=1) ----
    gemm_mfma<256, 64, 1><<<dim3(gm, 1), 256, 0, stream>>>(xbig, wb3, Hb, a3s, a3d, als, ald);
    aggregate_h1<<<nagg1, 256, 0, stream>>>(Hb, als, ald, offs, csr, b3, out, Nn);
}

// Round 4
// 479.481 us; speedup vs baseline: 1.5247x; 1.0585x over previous
//
#include <hip/hip_runtime.h>
#include <hip/hip_bf16.h>

#define NEG_ATT 0.2f
#define NEG_ACT 0.01f

typedef __attribute__((ext_vector_type(8))) short short8;
typedef __attribute__((ext_vector_type(4))) float f32x4;

__device__ __forceinline__ unsigned short f2bf(float f) {
    unsigned int u = __float_as_uint(f);
    unsigned int r = (u + 0x7fff + ((u >> 16) & 1)) >> 16;  // RNE
    return (unsigned short)r;
}
__device__ __forceinline__ float b2f(unsigned short h) {
    return __uint_as_float((unsigned int)h << 16);
}

// ---------------- CSR build ----------------

__global__ void init_deg(int* deg, int Nn) {
    int t = blockIdx.x * 256 + threadIdx.x;
    if (t < Nn) deg[t] = 1;  // self loop
}

__global__ void count_edges(const int* __restrict__ ei, int* deg, int E) {
    int t = blockIdx.x * 256 + threadIdx.x;
    if (t < E) atomicAdd(&deg[ei[E + t]], 1);  // dst row
}

#define SCAN_CHUNK 1024
__global__ void scan1(const int* __restrict__ deg, int* __restrict__ offs,
                      int* blocksum, int Nn) {
    __shared__ int sh[256];
    int b = blockIdx.x, t = threadIdx.x;
    int base = b * SCAN_CHUNK + t * 4;
    int v[4];
    int s = 0;
    for (int j = 0; j < 4; j++) {
        int idx = base + j;
        v[j] = (idx < Nn) ? deg[idx] : 0;
        s += v[j];
    }
    sh[t] = s;
    __syncthreads();
    for (int off = 1; off < 256; off <<= 1) {
        int x = (t >= off) ? sh[t - off] : 0;
        __syncthreads();
        sh[t] += x;
        __syncthreads();
    }
    int excl = sh[t] - s;
    if (t == 255) blocksum[b] = sh[255];
    int run = excl;
    for (int j = 0; j < 4; j++) {
        int idx = base + j;
        if (idx < Nn) offs[idx] = run;
        run += v[j];
    }
}

__global__ void scan2(int* blocksum, int G) {
    if (threadIdx.x == 0 && blockIdx.x == 0) {
        int run = 0;
        for (int i = 0; i < G; i++) { int v = blocksum[i]; blocksum[i] = run; run += v; }
    }
}

__global__ void scan3(int* offs, const int* base, int* cursor, int Nn, int total) {
    int i = blockIdx.x * 256 + threadIdx.x;
    if (i < Nn) {
        int v = offs[i] + base[i >> 10];
        offs[i] = v;
        cursor[i] = v;
    }
    if (i == 0) offs[Nn] = total;
}

__global__ void fill_csr(const int* __restrict__ ei, int* cursor, int* csr, int* dcsr,
                         int E, int Nn) {
    int t = blockIdx.x * 256 + threadIdx.x;
    if (t < E) {
        int s = ei[t];
        int d = ei[E + t];
        int p = atomicAdd(&cursor[d], 1);
        csr[p] = s;
        dcsr[p] = d;
    } else if (t < E + Nn) {
        int nn = t - E;
        int p = atomicAdd(&cursor[nn], 1);
        csr[p] = nn;
        dcsr[p] = nn;
    }
}

// ---------------- per-edge softmax weights (no dependent chain later) ----------------

template <int HEADS>
__global__ __launch_bounds__(256) void edge_w(const int* __restrict__ csr,
                                              const int* __restrict__ dcsr,
                                              const float* __restrict__ als,
                                              const float* __restrict__ ald,
                                              float* __restrict__ wcsr, int Ep) {
    int t = blockIdx.x * 256 + threadIdx.x;
    if (t >= Ep) return;
    int s = csr[t], d = dcsr[t];
    if (HEADS == 4) {
        float4 a = *(const float4*)&als[s * 4];
        float4 b = *(const float4*)&ald[d * 4];
        float4 w;
        float e;
        e = a.x + b.x; e = e > 0.f ? e : NEG_ATT * e; w.x = __expf(e);
        e = a.y + b.y; e = e > 0.f ? e : NEG_ATT * e; w.y = __expf(e);
        e = a.z + b.z; e = e > 0.f ? e : NEG_ATT * e; w.z = __expf(e);
        e = a.w + b.w; e = e > 0.f ? e : NEG_ATT * e; w.w = __expf(e);
        *(float4*)&wcsr[(size_t)t * 4] = w;
    } else {
        float e = als[s] + ald[d];
        e = e > 0.f ? e : NEG_ATT * e;
        wcsr[t] = __expf(e);
    }
}

// ---------------- fp32 -> bf16 conversion ----------------

__global__ __launch_bounds__(256) void f2b8(const float* __restrict__ in,
                                            unsigned short* __restrict__ out,
                                            int n, int ntot) {
    int i = (blockIdx.x * 256 + threadIdx.x) * 8;
    if (i >= ntot) return;
    ushort4 lo, hi;
    if (i < n) {
        float4 a = *(const float4*)&in[i];
        float4 b = *(const float4*)&in[i + 4];
        lo = make_ushort4(f2bf(a.x), f2bf(a.y), f2bf(a.z), f2bf(a.w));
        hi = make_ushort4(f2bf(b.x), f2bf(b.y), f2bf(b.z), f2bf(b.w));
    } else {
        lo = make_ushort4(0, 0, 0, 0);
        hi = lo;
    }
    *(ushort4*)&out[i] = lo;
    *(ushort4*)&out[i + 4] = hi;
}

// all three weight matrices in one dispatch (elem counts are multiples of 8)
__global__ __launch_bounds__(256) void f2b_w3(const float* __restrict__ w1, unsigned short* o1, int n1,
                                              const float* __restrict__ w2, unsigned short* o2, int n2,
                                              const float* __restrict__ w3, unsigned short* o3, int n3) {
    int i = (blockIdx.x * 256 + threadIdx.x) * 8;
    const float* in;
    unsigned short* out;
    if (i < n1) { in = w1 + i; out = o1 + i; }
    else if (i < n1 + n2) { in = w2 + (i - n1); out = o2 + (i - n1); }
    else if (i < n1 + n2 + n3) { in = w3 + (i - n1 - n2); out = o3 + (i - n1 - n2); }
    else return;
    float4 a = *(const float4*)in;
    float4 b = *(const float4*)(in + 4);
    *(ushort4*)out = make_ushort4(f2bf(a.x), f2bf(a.y), f2bf(a.z), f2bf(a.w));
    *(ushort4*)(out + 4) = make_ushort4(f2bf(b.x), f2bf(b.y), f2bf(b.z), f2bf(b.w));
}

// ---------------- MFMA GEMM (TN) + fused attention-logit epilogue ----------------

template <int K, int CO, int HEADS>
__global__ __launch_bounds__(256) void gemm_mfma(
    const unsigned short* __restrict__ Xb, const unsigned short* __restrict__ Wb,
    unsigned short* __restrict__ Hb, const float* __restrict__ a_s,
    const float* __restrict__ a_d, float* __restrict__ als, float* __restrict__ ald) {
    constexpr int BM = 128, BN = 64, BK = 64, LD = 72, SLD = 68;
    __shared__ __align__(16) char smem[4 * 32 * SLD * 4];
    unsigned short* As = (unsigned short*)smem;
    unsigned short* Bs = As + BM * LD;
    int tid = threadIdx.x;
    int wave = tid >> 6, lane = tid & 63;
    int quad = lane >> 4, l16 = lane & 15;
    int m0 = blockIdx.x * BM, n0 = blockIdx.y * BN;
    int hd = blockIdx.y;
    int arow = tid >> 3;
    int achk = (tid & 7) * 8;
    f32x4 acc[2][4] = {};
    for (int k0 = 0; k0 < K; k0 += BK) {
        __syncthreads();
#pragma unroll
        for (int p = 0; p < 4; p++) {
            int r = arow + p * 32;
            *(int4*)&As[r * LD + achk] = *(const int4*)&Xb[(size_t)(m0 + r) * K + k0 + achk];
        }
#pragma unroll
        for (int p = 0; p < 2; p++) {
            int r = arow + p * 32;
            *(int4*)&Bs[r * LD + achk] = *(const int4*)&Wb[(size_t)(n0 + r) * K + k0 + achk];
        }
        __syncthreads();
#pragma unroll
        for (int ks = 0; ks < 2; ks++) {
            short8 af[2], bfr[4];
#pragma unroll
            for (int i = 0; i < 2; i++)
                af[i] = *(const short8*)&As[(wave * 32 + i * 16 + l16) * LD + ks * 32 + quad * 8];
#pragma unroll
            for (int j = 0; j < 4; j++)
                bfr[j] = *(const short8*)&Bs[(j * 16 + l16) * LD + ks * 32 + quad * 8];
#pragma unroll
            for (int i = 0; i < 2; i++)
#pragma unroll
                for (int j = 0; j < 4; j++)
                    acc[i][j] = __builtin_amdgcn_mfma_f32_16x16x32_bf16(af[i], bfr[j], acc[i][j], 0, 0, 0);
        }
    }
    __syncthreads();

    float asv[4], adv[4];
#pragma unroll
    for (int j = 0; j < 4; j++) {
        asv[j] = a_s[hd * 64 + j * 16 + l16];
        adv[j] = a_d[hd * 64 + j * 16 + l16];
    }
#pragma unroll
    for (int i = 0; i < 2; i++)
#pragma unroll
        for (int r = 0; r < 4; r++) {
            float ps = acc[i][0][r] * asv[0] + acc[i][1][r] * asv[1] +
                       acc[i][2][r] * asv[2] + acc[i][3][r] * asv[3];
            float pd = acc[i][0][r] * adv[0] + acc[i][1][r] * adv[1] +
                       acc[i][2][r] * adv[2] + acc[i][3][r] * adv[3];
#pragma unroll
            for (int mm = 1; mm < 16; mm <<= 1) {
                ps += __shfl_xor(ps, mm);
                pd += __shfl_xor(pd, mm);
            }
            if (l16 == 0) {
                int m = m0 + wave * 32 + i * 16 + quad * 4 + r;
                als[m * HEADS + hd] = ps;
                ald[m * HEADS + hd] = pd;
            }
        }

    float* stg = (float*)smem + wave * 32 * SLD;
#pragma unroll
    for (int i = 0; i < 2; i++)
#pragma unroll
        for (int j = 0; j < 4; j++)
#pragma unroll
            for (int r = 0; r < 4; r++)
                stg[(i * 16 + quad * 4 + r) * SLD + j * 16 + l16] = acc[i][j][r];
    int g = lane >> 3, c8 = (lane & 7) * 8;
#pragma unroll
    for (int p = 0; p < 4; p++) {
        int row = p * 8 + g;
        float4 v0 = *(const float4*)&stg[row * SLD + c8];
        float4 v1 = *(const float4*)&stg[row * SLD + c8 + 4];
        uint4 o;
        o.x = ((unsigned)f2bf(v0.y) << 16) | f2bf(v0.x);
        o.y = ((unsigned)f2bf(v0.w) << 16) | f2bf(v0.z);
        o.z = ((unsigned)f2bf(v1.y) << 16) | f2bf(v1.x);
        o.w = ((unsigned)f2bf(v1.w) << 16) | f2bf(v1.z);
        *(uint4*)&Hb[(size_t)(m0 + wave * 32 + row) * CO + n0 + c8] = o;
    }
}

// ---------------- edge-softmax aggregation (precomputed w, index prefetch, ILP4) ----

__global__ __launch_bounds__(256) void aggregate_h4(
    const unsigned short* __restrict__ Hb, const float* __restrict__ wcsr,
    const int* __restrict__ offs, const int* __restrict__ csr,
    const float* __restrict__ bias, float* __restrict__ Yout, int Nn) {
    int wave = threadIdx.x >> 6;
    int lane = threadIdx.x & 63;
    int n = blockIdx.x * 4 + wave;
    if (n >= Nn) return;
    int hd = lane >> 4;
    int c4 = lane * 4;
    int beg = offs[n], end = offs[n + 1];
    float4 acc = make_float4(0.f, 0.f, 0.f, 0.f);
    float den = 0.f;
    for (int b = beg; b < end; b += 64) {
        int cnt = min(64, end - b);
        int idx = 0;
        if (lane < cnt) idx = csr[b + lane];
        int j = 0;
        for (; j + 4 <= cnt; j += 4) {
            int s0 = __shfl(idx, j), s1 = __shfl(idx, j + 1);
            int s2 = __shfl(idx, j + 2), s3 = __shfl(idx, j + 3);
            float w0 = wcsr[(size_t)(b + j) * 4 + hd];
            float w1 = wcsr[(size_t)(b + j + 1) * 4 + hd];
            float w2 = wcsr[(size_t)(b + j + 2) * 4 + hd];
            float w3 = wcsr[(size_t)(b + j + 3) * 4 + hd];
            ushort4 h0 = *(const ushort4*)&Hb[(size_t)s0 * 256 + c4];
            ushort4 h1 = *(const ushort4*)&Hb[(size_t)s1 * 256 + c4];
            ushort4 h2 = *(const ushort4*)&Hb[(size_t)s2 * 256 + c4];
            ushort4 h3 = *(const ushort4*)&Hb[(size_t)s3 * 256 + c4];
            den += (w0 + w1) + (w2 + w3);
            acc.x += w0 * b2f(h0.x) + w1 * b2f(h1.x) + w2 * b2f(h2.x) + w3 * b2f(h3.x);
            acc.y += w0 * b2f(h0.y) + w1 * b2f(h1.y) + w2 * b2f(h2.y) + w3 * b2f(h3.y);
            acc.z += w0 * b2f(h0.z) + w1 * b2f(h1.z) + w2 * b2f(h2.z) + w3 * b2f(h3.z);
            acc.w += w0 * b2f(h0.w) + w1 * b2f(h1.w) + w2 * b2f(h2.w) + w3 * b2f(h3.w);
        }
        for (; j < cnt; j++) {
            int s = __shfl(idx, j);
            float w = wcsr[(size_t)(b + j) * 4 + hd];
            den += w;
            ushort4 hv = *(const ushort4*)&Hb[(size_t)s * 256 + c4];
            acc.x += w * b2f(hv.x); acc.y += w * b2f(hv.y);
            acc.z += w * b2f(hv.z); acc.w += w * b2f(hv.w);
        }
    }
    float inv = 1.f / den;
    float4 bv = *(const float4*)&bias[c4];
    float4 o = make_float4(acc.x * inv + bv.x, acc.y * inv + bv.y,
                           acc.z * inv + bv.z, acc.w * inv + bv.w);
    *(float4*)&Yout[(size_t)n * 256 + c4] = o;
}

// heads=1: 4 nodes/wave, 16 lanes x 4ch each. Writes final out.
__global__ __launch_bounds__(256) void aggregate_h1(
    const unsigned short* __restrict__ Hb, const float* __restrict__ wcsr,
    const int* __restrict__ offs, const int* __restrict__ csr,
    const float* __restrict__ bias, float* __restrict__ Yout, int Nn) {
    int wave = threadIdx.x >> 6;
    int lane = threadIdx.x & 63;
    int sub = lane >> 4, lane16 = lane & 15;
    int n = blockIdx.x * 16 + wave * 4 + sub;
    if (n >= Nn) return;
    int c4 = lane16 * 4;
    int beg = offs[n], end = offs[n + 1];
    float4 acc = make_float4(0.f, 0.f, 0.f, 0.f);
    float den = 0.f;
    for (int b = beg; b < end; b += 16) {
        int cnt = min(16, end - b);
        int idx = 0;
        if (lane16 < cnt) idx = csr[b + lane16];
        int j = 0;
        for (; j + 4 <= cnt; j += 4) {
            int s0 = __shfl(idx, (sub << 4) + j);
            int s1 = __shfl(idx, (sub << 4) + j + 1);
            int s2 = __shfl(idx, (sub << 4) + j + 2);
            int s3 = __shfl(idx, (sub << 4) + j + 3);
            float w0 = wcsr[b + j], w1 = wcsr[b + j + 1];
            float w2 = wcsr[b + j + 2], w3 = wcsr[b + j + 3];
            ushort4 h0 = *(const ushort4*)&Hb[(size_t)s0 * 64 + c4];
            ushort4 h1 = *(const ushort4*)&Hb[(size_t)s1 * 64 + c4];
            ushort4 h2 = *(const ushort4*)&Hb[(size_t)s2 * 64 + c4];
            ushort4 h3 = *(const ushort4*)&Hb[(size_t)s3 * 64 + c4];
            den += (w0 + w1) + (w2 + w3);
            acc.x += w0 * b2f(h0.x) + w1 * b2f(h1.x) + w2 * b2f(h2.x) + w3 * b2f(h3.x);
            acc.y += w0 * b2f(h0.y) + w1 * b2f(h1.y) + w2 * b2f(h2.y) + w3 * b2f(h3.y);
            acc.z += w0 * b2f(h0.z) + w1 * b2f(h1.z) + w2 * b2f(h2.z) + w3 * b2f(h3.z);
            acc.w += w0 * b2f(h0.w) + w1 * b2f(h1.w) + w2 * b2f(h2.w) + w3 * b2f(h3.w);
        }
        for (; j < cnt; j++) {
            int s = __shfl(idx, (sub << 4) + j);
            float w = wcsr[b + j];
            den += w;
            ushort4 hv = *(const ushort4*)&Hb[(size_t)s * 64 + c4];
            acc.x += w * b2f(hv.x); acc.y += w * b2f(hv.y);
            acc.z += w * b2f(hv.z); acc.w += w * b2f(hv.w);
        }
    }
    float inv = 1.f / den;
    float4 bv = *(const float4*)&bias[c4];
    float4 o = make_float4(acc.x * inv + bv.x, acc.y * inv + bv.y,
                           acc.z * inv + bv.z, acc.w * inv + bv.w);
    *(float4*)&Yout[(size_t)n * 64 + c4] = o;
}

// ---------------- BatchNorm (training-mode, biased var; no atomics) ----------------

__global__ __launch_bounds__(256) void bn_stats(const float* __restrict__ Y,
                                                float* __restrict__ partial, int Nn) {
    int ch = threadIdx.x;
    int g = blockIdx.x;
    int rows_per = (Nn + gridDim.x - 1) / gridDim.x;
    int r0 = g * rows_per;
    int r1 = min(r0 + rows_per, Nn);
    float s = 0.f, q = 0.f;
    for (int r = r0; r < r1; r++) {
        float v = Y[(size_t)r * 256 + ch];
        s += v;
        q += v * v;
    }
    partial[g * 512 + ch] = s;
    partial[g * 512 + 256 + ch] = q;
}

__global__ void bn_final(const float* __restrict__ partial, const float* __restrict__ gamma,
                         const float* __restrict__ beta, float* scale, float* shift, int Nn) {
    int ch = threadIdx.x;
    float s = 0.f, q = 0.f;
    for (int g = 0; g < 256; g++) {
        s += partial[g * 512 + ch];
        q += partial[g * 512 + 256 + ch];
    }
    float inv_n = 1.f / (float)Nn;
    float mu = s * inv_n;
    float var = q * inv_n - mu * mu;
    float sc = gamma[ch] * rsqrtf(var + 1e-5f);
    scale[ch] = sc;
    shift[ch] = beta[ch] - mu * sc;
}

template <bool RES, bool WF32>
__global__ __launch_bounds__(256) void bn_apply(const float* __restrict__ Y,
                                                const float* __restrict__ scale,
                                                const float* __restrict__ shift,
                                                const float* __restrict__ Res,
                                                float* __restrict__ Out,
                                                unsigned short* __restrict__ OutB,
                                                int total4, int total4pad) {
    int i = blockIdx.x * 256 + threadIdx.x;
    if (i >= total4pad) return;
    if (i >= total4) {
        *(ushort4*)&OutB[i * 4] = make_ushort4(0, 0, 0, 0);
        return;
    }
    float4 v = ((const float4*)Y)[i];
    int cb = (i * 4) & 255;
    float4 sc = *(const float4*)&scale[cb];
    float4 sh = *(const float4*)&shift[cb];
    float4 o;
    o.x = sc.x * v.x + sh.x; o.x = o.x > 0.f ? o.x : NEG_ACT * o.x;
    o.y = sc.y * v.y + sh.y; o.y = o.y > 0.f ? o.y : NEG_ACT * o.y;
    o.z = sc.z * v.z + sh.z; o.z = o.z > 0.f ? o.z : NEG_ACT * o.z;
    o.w = sc.w * v.w + sh.w; o.w = o.w > 0.f ? o.w : NEG_ACT * o.w;
    if (RES) {
        float4 r = ((const float4*)Res)[i];
        o.x += r.x; o.y += r.y; o.z += r.z; o.w += r.w;
    }
    if (WF32) ((float4*)Out)[i] = o;
    *(ushort4*)&OutB[i * 4] = make_ushort4(f2bf(o.x), f2bf(o.y), f2bf(o.z), f2bf(o.w));
}

// ---------------- launch ----------------

extern "C" void kernel_launch(void* const* d_in, const int* in_sizes, int n_in,
                              void* d_out, int out_size, void* d_ws, size_t ws_size,
                              hipStream_t stream) {
    const float* x    = (const float*)d_in[0];
    const int*   ei   = (const int*)d_in[1];
    const float* W1   = (const float*)d_in[2];
    const float* a1s  = (const float*)d_in[3];
    const float* a1d  = (const float*)d_in[4];
    const float* b1   = (const float*)d_in[5];
    const float* W2   = (const float*)d_in[6];
    const float* a2s  = (const float*)d_in[7];
    const float* a2d  = (const float*)d_in[8];
    const float* b2   = (const float*)d_in[9];
    const float* W3   = (const float*)d_in[10];
    const float* a3s  = (const float*)d_in[11];
    const float* a3d  = (const float*)d_in[12];
    const float* b3   = (const float*)d_in[13];
    const float* gamma = (const float*)d_in[14];
    const float* beta  = (const float*)d_in[15];
    float* out = (float*)d_out;

    const int Nn = in_sizes[0] / 128;
    const int E  = in_sizes[1] / 2;
    const int Ep = E + Nn;
    const int Mpad = (Nn + 127) & ~127;

    size_t off = 0;
    char* base = (char*)d_ws;
    auto alloc = [&](size_t bytes) -> void* {
        void* p = base + off;
        off = (off + bytes + 255) & ~(size_t)255;
        return p;
    };
    unsigned short* Hb   = (unsigned short*)alloc((size_t)Mpad * 256 * 2);
    float* bufB   = (float*)alloc((size_t)Nn * 256 * 4);
    float* bufC   = (float*)alloc((size_t)Nn * 256 * 4);
    unsigned short* xb1  = (unsigned short*)alloc((size_t)Mpad * 128 * 2);
    unsigned short* xbig = (unsigned short*)alloc((size_t)Mpad * 256 * 2);
    unsigned short* wb1  = (unsigned short*)alloc((size_t)256 * 128 * 2);
    unsigned short* wb2  = (unsigned short*)alloc((size_t)256 * 256 * 2);
    unsigned short* wb3  = (unsigned short*)alloc((size_t)64 * 256 * 2);
    float* als    = (float*)alloc((size_t)Mpad * 4 * 4);
    float* ald    = (float*)alloc((size_t)Mpad * 4 * 4);
    int*   deg    = (int*)alloc((size_t)Nn * 4);
    int*   offs   = (int*)alloc((size_t)(Nn + 1) * 4);
    int*   cursor = (int*)alloc((size_t)Nn * 4);
    int*   bsum   = (int*)alloc(64 * 4);
    int*   csr    = (int*)alloc((size_t)Ep * 4);
    int*   dcsr   = (int*)alloc((size_t)Ep * 4);
    float* wcsr   = (float*)alloc((size_t)Ep * 4 * 4);
    float* partial = (float*)alloc(256 * 512 * 4);
    float* scale  = (float*)alloc(256 * 4);
    float* shift  = (float*)alloc(256 * 4);
    (void)ws_size;

    const int G = (Nn + SCAN_CHUNK - 1) / SCAN_CHUNK;

    // ---- CSR build (shared by all 3 layers) ----
    init_deg<<<(Nn + 255) / 256, 256, 0, stream>>>(deg, Nn);
    count_edges<<<(E + 255) / 256, 256, 0, stream>>>(ei, deg, E);
    scan1<<<G, 256, 0, stream>>>(deg, offs, bsum, Nn);
    scan2<<<1, 64, 0, stream>>>(bsum, G);
    scan3<<<(Nn + 255) / 256, 256, 0, stream>>>(offs, bsum, cursor, Nn, Ep);
    fill_csr<<<(Ep + 255) / 256, 256, 0, stream>>>(ei, cursor, csr, dcsr, E, Nn);

    // ---- bf16 conversions ----
    {
        int ntot = Mpad * 128;
        f2b8<<<(ntot / 8 + 255) / 256, 256, 0, stream>>>(x, xb1, Nn * 128, ntot);
        int wtot = 256 * 128 + 256 * 256 + 64 * 256;
        f2b_w3<<<(wtot / 8 + 255) / 256, 256, 0, stream>>>(W1, wb1, 256 * 128,
                                                           W2, wb2, 256 * 256,
                                                           W3, wb3, 64 * 256);
    }

    const int gm = Mpad / 128;
    const int nagg4 = (Nn + 3) / 4;
    const int nagg1 = (Nn + 15) / 16;
    const int gedge = (Ep + 255) / 256;
    const int total4 = Nn * 64;
    const int total4pad = Mpad * 64;
    const int napply = (total4pad + 255) / 256;

    // ---- Layer 1 ----
    gemm_mfma<128, 256, 4><<<dim3(gm, 4), 256, 0, stream>>>(xb1, wb1, Hb, a1s, a1d, als, ald);
    edge_w<4><<<gedge, 256, 0, stream>>>(csr, dcsr, als, ald, wcsr, Ep);
    aggregate_h4<<<nagg4, 256, 0, stream>>>(Hb, wcsr, offs, csr, b1, bufB, Nn);
    bn_stats<<<256, 256, 0, stream>>>(bufB, partial, Nn);
    bn_final<<<1, 256, 0, stream>>>(partial, gamma, beta, scale, shift, Nn);
    bn_apply<false, true><<<napply, 256, 0, stream>>>(bufB, scale, shift, nullptr, bufC, xbig,
                                                      total4, total4pad);

    // ---- Layer 2 ----
    gemm_mfma<256, 256, 4><<<dim3(gm, 4), 256, 0, stream>>>(xbig, wb2, Hb, a2s, a2d, als, ald);
    edge_w<4><<<gedge, 256, 0, stream>>>(csr, dcsr, als, ald, wcsr, Ep);
    aggregate_h4<<<nagg4, 256, 0, stream>>>(Hb, wcsr, offs, csr, b2, bufB, Nn);
    bn_stats<<<256, 256, 0, stream>>>(bufB, partial, Nn);
    bn_final<<<1, 256, 0, stream>>>(partial, gamma, beta, scale, shift, Nn);
    bn_apply<true, false><<<napply, 256, 0, stream>>>(bufB, scale, shift, bufC, nullptr, xbig,
                                                      total4, total4pad);

    // ---- Layer 3 ----
    gemm_mfma<256, 64, 1><<<dim3(gm, 1), 256, 0, stream>>>(xbig, wb3, Hb, a3s, a3d, als, ald);
    edge_w<1><<<gedge, 256, 0, stream>>>(csr, dcsr, als, ald, wcsr, Ep);
    aggregate_h1<<<nagg1, 256, 0, stream>>>(Hb, wcsr, offs, csr, b3, out, Nn);
}